// Round 13
// baseline (43.938 us; speedup 1.0000x reference)
//
#include <hip/hip_runtime.h>

typedef float  v4f    __attribute__((ext_vector_type(4)));
typedef float  f32x4  __attribute__((ext_vector_type(4)));
typedef short  bf16x8 __attribute__((ext_vector_type(8)));

namespace {
constexpr int XBSTR = 264;   // xbf row stride (shorts)
constexpr int XDT   = 24;    // xdT row stride (shorts); 48 B, b128-aligned
constexpr int MWC   = 129;   // mw row stride (f32)
constexpr int ATS   = 258;   // att row stride (shorts)
constexpr int MSTR  = 72;    // mbf/abf row stride (shorts)
constexpr int FRAG_SLOTS = 5120;

__device__ __forceinline__ float fsilu(float v){ return v/(1.f+__expf(-v)); }
__device__ __forceinline__ float fsigm(float v){ return 1.f/(1.f+__expf(-v)); }

// fp32 pair -> packed bf16x2 via the HW instruction (1 VALU op / 2 elems)
__device__ __forceinline__ unsigned f2bf2(float a, float b){
  unsigned r;
  asm("v_cvt_pk_bf16_f32 %0, %1, %2" : "=v"(r) : "v"(a), "v"(b));
  return r;
}
__device__ __forceinline__ short f2bf(float f){   // scalar: RNE, matches cvt_pk
  unsigned u = __builtin_bit_cast(unsigned, f);
  return (short)((u + 0x7FFFu + ((u>>16)&1u)) >> 16);
}
__device__ __forceinline__ float bf2f(short s){
  unsigned u = ((unsigned)(unsigned short)s) << 16;
  return __builtin_bit_cast(float, u);
}

// ---- B-fragment getters: frag table in ws (fast) or on-the-fly (fallback) ----
template<bool USE_WS>
__device__ __forceinline__ bf16x8 get_bd(const bf16x8* wsf, const float* Wd,
                                         int nt, int ks, int l){
  if constexpr (USE_WS) return wsf[(nt*8 + ks)*64 + l];
  bf16x8 f;
  #pragma unroll
  for (int j = 0; j < 8; ++j) f[j] = f2bf(Wd[(ks*32 + (l>>4)*8 + j)*64 + nt*16 + (l&15)]);
  return f;
}
template<bool USE_WS>
__device__ __forceinline__ bf16x8 get_bc(const bf16x8* wsf, const float* Wc,
                                         int nt, int ks, int l){
  if constexpr (USE_WS) return wsf[2048 + (nt*2 + ks)*64 + l];
  const int col = nt*16 + (l&15), cw = col>>6, co = col&63;
  bf16x8 f;
  #pragma unroll
  for (int j = 0; j < 8; ++j) f[j] = f2bf(Wc[co*128 + cw*64 + ks*32 + (l>>4)*8 + j]);
  return f;
}
template<bool USE_WS>
__device__ __forceinline__ bf16x8 get_ba(const bf16x8* wsf, const float* Wa,
                                         int nt, int ks, int l){
  if constexpr (USE_WS) return wsf[3072 + (nt*2 + ks)*64 + l];
  const int col = nt*16 + (l&15);
  bf16x8 f;
  #pragma unroll
  for (int j = 0; j < 8; ++j) f[j] = f2bf(Wa[(ks*32 + (l>>4)*8 + j)*256 + col]);
  return f;
}
}

// ---- pre-kernel: pack Wd/Wc/Wa into bf16 MFMA B-fragment tables in ws ----
__global__ __launch_bounds__(256)
void pack_frags(const float* __restrict__ Wd, const float* __restrict__ Wc,
                const float* __restrict__ Wa, bf16x8* __restrict__ wsf)
{
  const int e  = blockIdx.x*256 + threadIdx.x;      // 0..5119
  const int l  = e & 63;
  const int fi = e >> 6;                            // 0..79
  bf16x8 f;
  if (fi < 32) {                                    // Bd: nt(4) x ks(8)
    const int nt = fi >> 3, ks = fi & 7;
    #pragma unroll
    for (int j = 0; j < 8; ++j) f[j] = f2bf(Wd[(ks*32 + (l>>4)*8 + j)*64 + nt*16 + (l&15)]);
  } else if (fi < 48) {                             // Bc: nt(8) x ks(2)
    const int idx = fi - 32, nt = idx >> 1, ks = idx & 1;
    const int col = nt*16 + (l&15), cw = col>>6, co = col&63;
    #pragma unroll
    for (int j = 0; j < 8; ++j) f[j] = f2bf(Wc[co*128 + cw*64 + ks*32 + (l>>4)*8 + j]);
  } else {                                          // Ba: nt(16) x ks(2)
    const int idx = fi - 48, nt = idx >> 1, ks = idx & 1;
    const int col = nt*16 + (l&15);
    #pragma unroll
    for (int j = 0; j < 8; ++j) f[j] = f2bf(Wa[(ks*32 + (l>>4)*8 + j)*256 + col]);
  }
  wsf[e] = f;
}

template<bool USE_WS>
__global__ __launch_bounds__(256, 4)
void fused_gnn_v11(const float* __restrict__ x,
                   const float* __restrict__ Wd, const float* __restrict__ bd,
                   const float* __restrict__ bn1s, const float* __restrict__ bn1b,
                   const float* __restrict__ bn1m, const float* __restrict__ bn1v,
                   const float* __restrict__ Wc,
                   const float* __restrict__ bn2s, const float* __restrict__ bn2b,
                   const float* __restrict__ bn2m, const float* __restrict__ bn2v,
                   const float* __restrict__ Wa, const float* __restrict__ ba,
                   const bf16x8* __restrict__ wsf,
                   float* __restrict__ out)
{
  // ~38.6 KB static LDS -> 4 blocks/CU (16 waves)
  __shared__ short xbf[2][18*XBSTR];                // per batch; row 17 = tail-clamp garbage
  __shared__ __align__(16) char uni_raw[2][3072];   // union: xdT bf16[64][24] | att bf16[5][258]
  __shared__ float mw[2][5*MWC];
  __shared__ short mbf[2][16*MSTR];                 // rows 5-15 garbage
  __shared__ short abf[2][16*MSTR];

  const int tid  = threadIdx.x;
  const int l    = tid & 63;
  const int wv   = tid >> 6;            // wave 0..3
  const int arow = l & 15;
  const int ak8  = (l >> 4) * 8;
  const int b0   = blockIdx.x * 2;      // two batches per block
  const int colA = wv*16 + arow;

  // ---- per-lane BN affines in registers (b_down folded into bn1 bias) ----
  const float a1r = bn1s[colA] * rsqrtf(bn1v[colA] + 1e-5f);
  const float b1r = (bd[colA] - bn1m[colA])*a1r + bn1b[colA];
  const float a2r = bn2s[l] * rsqrtf(bn2v[l] + 1e-5f);
  const float b2r = bn2b[l] - bn2m[l]*a2r;

  // ---- stage both batches: global -> regs (all loads in flight) -> bf16 LDS ----
  {
    v4f xr[2][5];
    #pragma unroll
    for (int q = 0; q < 2; ++q) {
      const v4f* x4 = (const v4f*)(x + (size_t)(b0+q) * 4352);
      #pragma unroll
      for (int i = 0; i < 5; ++i) {
        const int idx = i*256 + tid;
        if (idx < 1088) xr[q][i] = x4[idx];
      }
    }
    #pragma unroll
    for (int q = 0; q < 2; ++q) {
      #pragma unroll
      for (int i = 0; i < 5; ++i) {
        const int idx = i*256 + tid;
        if (idx < 1088) {
          const v4f v = xr[q][i];
          const int r = idx >> 6, c4 = (idx & 63) * 4;
          uint2 u; u.x = f2bf2(v.x, v.y); u.y = f2bf2(v.z, v.w);
          *(uint2*)&xbf[q][r*XBSTR + c4] = u;
        }
      }
    }
  }
  __syncthreads();                                   // bar1: stage -> A

  // ---- Phase A (MFMA x2 batches): xd = silu(bn1(x @ Wd)); epilogue -> xdT ----
  {
    f32x4 acc0[2] = {{0.f,0.f,0.f,0.f},{0.f,0.f,0.f,0.f}};
    f32x4 acc1[2] = {{0.f,0.f,0.f,0.f},{0.f,0.f,0.f,0.f}};
    const int rowT = (arow == 0) ? 16 : 17;
    #pragma unroll
    for (int h = 0; h < 2; ++h) {
      bf16x8 Bd[4];
      #pragma unroll
      for (int k4 = 0; k4 < 4; ++k4) Bd[k4] = get_bd<USE_WS>(wsf, Wd, wv, h*4 + k4, l);
      #pragma unroll
      for (int k4 = 0; k4 < 4; ++k4) {
        const int ks = h*4 + k4;
        #pragma unroll
        for (int q = 0; q < 2; ++q) {
          bf16x8 a0 = *(const bf16x8*)&xbf[q][arow*XBSTR + ks*32 + ak8];
          acc0[q] = __builtin_amdgcn_mfma_f32_16x16x32_bf16(a0, Bd[k4], acc0[q], 0, 0, 0);
          bf16x8 a1 = *(const bf16x8*)&xbf[q][rowT*XBSTR + ks*32 + ak8];
          acc1[q] = __builtin_amdgcn_mfma_f32_16x16x32_bf16(a1, Bd[k4], acc1[q], 0, 0, 0);
        }
      }
    }
    #pragma unroll
    for (int q = 0; q < 2; ++q) {
      short* xdT = (short*)uni_raw[q];
      const float s0 = fsilu(acc0[q][0]*a1r + b1r);
      const float s1 = fsilu(acc0[q][1]*a1r + b1r);
      const float s2 = fsilu(acc0[q][2]*a1r + b1r);
      const float s3 = fsilu(acc0[q][3]*a1r + b1r);
      uint2 u; u.x = f2bf2(s0, s1); u.y = f2bf2(s2, s3);
      *(uint2*)&xdT[colA*XDT + (l>>4)*4] = u;
      if ((l >> 4) == 0)
        xdT[colA*XDT + 16] = f2bf(fsilu(acc1[q][0]*a1r + b1r));
    }
  }
  __syncthreads();                                   // bar2: A -> B1

  // ---- prefetch B2 weight frags (shared by both batches) ----
  bf16x8 BcT[2][2];
  #pragma unroll
  for (int t = 0; t < 2; ++t)
    #pragma unroll
    for (int ks = 0; ks < 2; ++ks)
      BcT[t][ks] = get_bc<USE_WS>(wsf, Wc, wv*2 + t, ks, l);

  // ---- Phase B1 (split x2): wave wv computes group g=wv; wave 0 also g=4 ----
  #pragma unroll
  for (int q = 0; q < 2; ++q) {
    const short* xdT = (const short*)uni_raw[q];
    const int i = l;
    #define XDV(r) bf2f(xdT[i*XDT + (r)])
    if (wv == 0) {
      mbf[q][0*MSTR + i] = f2bf((XDV(0)+XDV(1)+XDV(2)+XDV(3)+XDV(4))*0.2f);
      mbf[q][4*MSTR + i] = f2bf((XDV(12)+XDV(14)+XDV(16))*(1.f/3.f));
    } else if (wv == 1) {
      mbf[q][1*MSTR + i] = f2bf((XDV(5)+XDV(7)+XDV(9))*(1.f/3.f));
    } else if (wv == 2) {
      mbf[q][2*MSTR + i] = f2bf((XDV(6)+XDV(8)+XDV(10))*(1.f/3.f));
    } else {
      mbf[q][3*MSTR + i] = f2bf((XDV(11)+XDV(13)+XDV(15))*(1.f/3.f));
    }
    #undef XDV
  }
  __syncthreads();                                   // bar3: B1 -> B2

  // ---- Phase B2 (MFMA x2): mw = means @ [Wc1|Wc2], M=5, N=128 ----
  {
    bf16x8 am[2][2];
    #pragma unroll
    for (int q = 0; q < 2; ++q)
      #pragma unroll
      for (int ks = 0; ks < 2; ++ks)
        am[q][ks] = *(const bf16x8*)&mbf[q][arow*MSTR + ks*32 + ak8];
    #pragma unroll
    for (int t = 0; t < 2; ++t) {
      const int nt = wv*2 + t;
      #pragma unroll
      for (int q = 0; q < 2; ++q) {
        f32x4 acc = {0.f,0.f,0.f,0.f};
        #pragma unroll
        for (int ks = 0; ks < 2; ++ks)
          acc = __builtin_amdgcn_mfma_f32_16x16x32_bf16(am[q][ks], BcT[t][ks], acc, 0, 0, 0);
        #pragma unroll
        for (int j = 0; j < 4; ++j) {
          const int g = (l>>4)*4 + j;
          if (g < 5) mw[q][g*MWC + nt*16 + arow] = acc[j];
        }
      }
    }
  }
  __syncthreads();                                   // bar4: B2 -> B3

  // ---- prefetch all phase-E weight frags (shared by both batches) ----
  bf16x8 BaT[4][2];
  #pragma unroll
  for (int t = 0; t < 4; ++t)
    #pragma unroll
    for (int ks = 0; ks < 2; ++ks)
      BaT[t][ks] = get_ba<USE_WS>(wsf, Wa, wv*4 + t, ks, l);

  // ---- Phase B3 (split x2): wave wv computes g=wv; wave 0 also g=4 ----
  #pragma unroll
  for (int q = 0; q < 2; ++q) {
    const int o = l;
    float m2c[5];
    #pragma unroll
    for (int cc = 0; cc < 5; ++cc) m2c[cc] = mw[q][cc*MWC + 64 + o];
    auto doG = [&](int g){
      const float bse = mw[q][g*MWC + o] - m2c[g];
      float s = 0.f;
      #pragma unroll
      for (int cc = 0; cc < 5; ++cc) {
        if (cc != g) s += fsilu((bse + m2c[cc])*a2r + b2r);
      }
      abf[q][g*MSTR + o] = f2bf(s);
    };
    if (wv == 0) { doG(0); doG(4); }
    else if (wv == 1) doG(1);
    else if (wv == 2) doG(2);
    else doG(3);
  }
  __syncthreads();                                   // bar5: B3 -> E

  // ---- Phase E (MFMA x2): att = sigmoid(agg @ Wa + ba), M=5, N=256 ----
  {
    bf16x8 ae[2][2];
    #pragma unroll
    for (int q = 0; q < 2; ++q)
      #pragma unroll
      for (int ks = 0; ks < 2; ++ks)
        ae[q][ks] = *(const bf16x8*)&abf[q][arow*MSTR + ks*32 + ak8];
    #pragma unroll
    for (int t = 0; t < 4; ++t) {
      const int nt = wv*4 + t;
      const int colE = nt*16 + arow;
      const float bav = ba[colE];
      #pragma unroll
      for (int q = 0; q < 2; ++q) {
        short* att = (short*)uni_raw[q];
        f32x4 acc = {0.f,0.f,0.f,0.f};
        #pragma unroll
        for (int ks = 0; ks < 2; ++ks)
          acc = __builtin_amdgcn_mfma_f32_16x16x32_bf16(ae[q][ks], BaT[t][ks], acc, 0, 0, 0);
        #pragma unroll
        for (int j = 0; j < 4; ++j) {
          const int g = (l>>4)*4 + j;
          if (g < 5) att[g*ATS + colE] = f2bf(fsigm(acc[j] + bav));
        }
      }
    }
  }
  __syncthreads();                                   // bar6: E -> F

  // ---- Phase F (x2): out[k][c] = bf16(x)[k][c] * att[GOF[k]][c] ----
  {
    const int c = tid;
    constexpr int GOF[17] = {0,0,0,0,0,1,2,1,2,1,2,3,4,3,4,3,4};
    #pragma unroll
    for (int q = 0; q < 2; ++q) {
      const short* att = (const short*)uni_raw[q];
      float a5[5];
      #pragma unroll
      for (int g = 0; g < 5; ++g) a5[g] = bf2f(att[g*ATS + c]);
      float* og = out + (size_t)(b0+q)*4352 + c;
      #pragma unroll
      for (int k = 0; k < 17; ++k)
        og[k*256] = bf2f(xbf[q][k*XBSTR + c]) * a5[GOF[k]];
    }
  }
}

extern "C" void kernel_launch(void* const* d_in, const int* in_sizes, int n_in,
                              void* d_out, int out_size, void* d_ws, size_t ws_size,
                              hipStream_t stream) {
    (void)n_in; (void)out_size;
    const float* x   = (const float*)d_in[0];
    const float* Wd  = (const float*)d_in[1];
    const float* bd  = (const float*)d_in[2];
    const float* s1  = (const float*)d_in[3];
    const float* b1  = (const float*)d_in[4];
    const float* m1  = (const float*)d_in[5];
    const float* v1  = (const float*)d_in[6];
    const float* Wc  = (const float*)d_in[7];
    const float* s2  = (const float*)d_in[8];
    const float* b2  = (const float*)d_in[9];
    const float* m2  = (const float*)d_in[10];
    const float* v2  = (const float*)d_in[11];
    const float* Wa  = (const float*)d_in[12];
    const float* ba  = (const float*)d_in[13];

    const int Btot = in_sizes[0] / (17 * 256);   // 4096 -> two batches per block
    const int GRID = Btot / 2;                   // 2048 blocks
    bf16x8* wsf = (bf16x8*)d_ws;

    if (ws_size >= (size_t)FRAG_SLOTS * 16) {
        pack_frags<<<FRAG_SLOTS/256, 256, 0, stream>>>(Wd, Wc, Wa, wsf);
        fused_gnn_v11<true><<<GRID, 256, 0, stream>>>(
            x, Wd, bd, s1, b1, m1, v1, Wc, s2, b2, m2, v2, Wa, ba,
            wsf, (float*)d_out);
    } else {
        fused_gnn_v11<false><<<GRID, 256, 0, stream>>>(
            x, Wd, bd, s1, b1, m1, v1, Wc, s2, b2, m2, v2, Wa, ba,
            wsf, (float*)d_out);
    }
}

// Round 14
// 41.524 us; speedup vs baseline: 1.0581x; 1.0581x over previous
//
#include <hip/hip_runtime.h>

typedef float  v4f    __attribute__((ext_vector_type(4)));
typedef float  f32x4  __attribute__((ext_vector_type(4)));
typedef short  bf16x8 __attribute__((ext_vector_type(8)));
typedef short  bf16x4 __attribute__((ext_vector_type(4)));

namespace {
constexpr int XBSTR = 264;   // xbf row stride (shorts)
constexpr int XDT   = 24;    // xdT row stride (shorts); 48 B, b128-aligned
constexpr int MWC   = 129;   // mw row stride (f32)
constexpr int ATS   = 260;   // att row stride (shorts); 520 B, 8B-aligned rows for b64 reads
constexpr int MSTR  = 72;    // mbf/abf row stride (shorts)
constexpr int FRAG_SLOTS = 5120;

__device__ __forceinline__ float fsilu(float v){ return v/(1.f+__expf(-v)); }
__device__ __forceinline__ float fsigm(float v){ return 1.f/(1.f+__expf(-v)); }

// fp32 pair -> packed bf16x2 via the HW instruction (1 VALU op / 2 elems)
__device__ __forceinline__ unsigned f2bf2(float a, float b){
  unsigned r;
  asm("v_cvt_pk_bf16_f32 %0, %1, %2" : "=v"(r) : "v"(a), "v"(b));
  return r;
}
__device__ __forceinline__ short f2bf(float f){   // scalar: RNE, matches cvt_pk
  unsigned u = __builtin_bit_cast(unsigned, f);
  return (short)((u + 0x7FFFu + ((u>>16)&1u)) >> 16);
}
__device__ __forceinline__ float bf2f(short s){
  unsigned u = ((unsigned)(unsigned short)s) << 16;
  return __builtin_bit_cast(float, u);
}

// ---- B-fragment getters: frag table in ws (fast) or on-the-fly (fallback) ----
template<bool USE_WS>
__device__ __forceinline__ bf16x8 get_bd(const bf16x8* wsf, const float* Wd,
                                         int nt, int ks, int l){
  if constexpr (USE_WS) return wsf[(nt*8 + ks)*64 + l];
  bf16x8 f;
  #pragma unroll
  for (int j = 0; j < 8; ++j) f[j] = f2bf(Wd[(ks*32 + (l>>4)*8 + j)*64 + nt*16 + (l&15)]);
  return f;
}
template<bool USE_WS>
__device__ __forceinline__ bf16x8 get_bc(const bf16x8* wsf, const float* Wc,
                                         int nt, int ks, int l){
  if constexpr (USE_WS) return wsf[2048 + (nt*2 + ks)*64 + l];
  const int col = nt*16 + (l&15), cw = col>>6, co = col&63;
  bf16x8 f;
  #pragma unroll
  for (int j = 0; j < 8; ++j) f[j] = f2bf(Wc[co*128 + cw*64 + ks*32 + (l>>4)*8 + j]);
  return f;
}
template<bool USE_WS>
__device__ __forceinline__ bf16x8 get_ba(const bf16x8* wsf, const float* Wa,
                                         int nt, int ks, int l){
  if constexpr (USE_WS) return wsf[3072 + (nt*2 + ks)*64 + l];
  const int col = nt*16 + (l&15);
  bf16x8 f;
  #pragma unroll
  for (int j = 0; j < 8; ++j) f[j] = f2bf(Wa[(ks*32 + (l>>4)*8 + j)*256 + col]);
  return f;
}
}

// ---- pre-kernel: pack Wd/Wc/Wa into bf16 MFMA B-fragment tables in ws ----
__global__ __launch_bounds__(256)
void pack_frags(const float* __restrict__ Wd, const float* __restrict__ Wc,
                const float* __restrict__ Wa, bf16x8* __restrict__ wsf)
{
  const int e  = blockIdx.x*256 + threadIdx.x;      // 0..5119
  const int l  = e & 63;
  const int fi = e >> 6;                            // 0..79
  bf16x8 f;
  if (fi < 32) {                                    // Bd: nt(4) x ks(8)
    const int nt = fi >> 3, ks = fi & 7;
    #pragma unroll
    for (int j = 0; j < 8; ++j) f[j] = f2bf(Wd[(ks*32 + (l>>4)*8 + j)*64 + nt*16 + (l&15)]);
  } else if (fi < 48) {                             // Bc: nt(8) x ks(2)
    const int idx = fi - 32, nt = idx >> 1, ks = idx & 1;
    const int col = nt*16 + (l&15), cw = col>>6, co = col&63;
    #pragma unroll
    for (int j = 0; j < 8; ++j) f[j] = f2bf(Wc[co*128 + cw*64 + ks*32 + (l>>4)*8 + j]);
  } else {                                          // Ba: nt(16) x ks(2)
    const int idx = fi - 48, nt = idx >> 1, ks = idx & 1;
    const int col = nt*16 + (l&15);
    #pragma unroll
    for (int j = 0; j < 8; ++j) f[j] = f2bf(Wa[(ks*32 + (l>>4)*8 + j)*256 + col]);
  }
  wsf[e] = f;
}

template<bool USE_WS>
__global__ __launch_bounds__(256, 5)
void fused_gnn_v12(const float* __restrict__ x,
                   const float* __restrict__ Wd, const float* __restrict__ bd,
                   const float* __restrict__ bn1s, const float* __restrict__ bn1b,
                   const float* __restrict__ bn1m, const float* __restrict__ bn1v,
                   const float* __restrict__ Wc,
                   const float* __restrict__ bn2s, const float* __restrict__ bn2b,
                   const float* __restrict__ bn2m, const float* __restrict__ bn2v,
                   const float* __restrict__ Wa, const float* __restrict__ ba,
                   const bf16x8* __restrict__ wsf,
                   float* __restrict__ out)
{
  // ~19.8 KB static LDS
  __shared__ short xbf[18*XBSTR];                   // 9504 B; row 17 = tail-clamp garbage target
  __shared__ __align__(16) char uni_raw[3072];      // union: xdT bf16[64][24] | att bf16[5][260]
  __shared__ float mw[5*MWC];                       // 2580 B
  __shared__ short mbf[16*MSTR];                    // 2304 B (rows 5-15 garbage)
  __shared__ short abf[16*MSTR];                    // 2304 B

  short* xdT = (short*)uni_raw;   // dead after B1 (bar3..5 separate from att writes)
  short* att = (short*)uni_raw;

  const int tid  = threadIdx.x;
  const int l    = tid & 63;
  const int wv   = tid >> 6;            // wave 0..3
  const int arow = l & 15;
  const int ak8  = (l >> 4) * 8;
  const int b    = blockIdx.x;          // one batch per block
  const int colA = wv*16 + arow;

  // ---- per-lane BN affines in registers (b_down folded into bn1 bias) ----
  const float a1r = bn1s[colA] * rsqrtf(bn1v[colA] + 1e-5f);
  const float b1r = (bd[colA] - bn1m[colA])*a1r + bn1b[colA];
  const float a2r = bn2s[l] * rsqrtf(bn2v[l] + 1e-5f);
  const float b2r = bn2b[l] - bn2m[l]*a2r;

  // ---- stage x: keep f32 in regs (reused by phase F) + write bf16 LDS copy ----
  // thread's slots: rows r0+4i (i=0..3) at column-quad c4 = l*4; tid<64 also row 16.
  const int c4 = l*4;
  const int r0 = tid >> 6;
  v4f xr0, xr1, xr2, xr3, xr4;
  {
    const v4f* x4 = (const v4f*)(x + (size_t)b * 4352);
    xr0 = x4[tid];        xr1 = x4[256 + tid];
    xr2 = x4[512 + tid];  xr3 = x4[768 + tid];
    if (tid < 64) xr4 = x4[1024 + tid];
    auto store4 = [&](v4f v, int r){
      uint2 u; u.x = f2bf2(v.x, v.y); u.y = f2bf2(v.z, v.w);
      *(uint2*)&xbf[r*XBSTR + c4] = u;
    };
    store4(xr0, r0);      store4(xr1, r0 + 4);
    store4(xr2, r0 + 8);  store4(xr3, r0 + 12);
    if (tid < 64) store4(xr4, 16);
  }
  __syncthreads();                                   // bar1: stage -> A

  // ---- Phase A (MFMA): xd = silu(bn1(x @ Wd)), M=17, N=64, K=256; epilogue -> xdT ----
  {
    f32x4 acc0 = {0.f,0.f,0.f,0.f};                  // rows 0..15
    f32x4 acc1 = {0.f,0.f,0.f,0.f};                  // tail tile: row 0 = batch row 16
    const int rowT = (arow == 0) ? 16 : 17;          // tail rows 1..15 read garbage row 17, discarded
    #pragma unroll
    for (int h = 0; h < 2; ++h) {
      bf16x8 Bd[4];
      #pragma unroll
      for (int k4 = 0; k4 < 4; ++k4) Bd[k4] = get_bd<USE_WS>(wsf, Wd, wv, h*4 + k4, l);
      #pragma unroll
      for (int k4 = 0; k4 < 4; ++k4) {
        const int ks = h*4 + k4;
        bf16x8 a0 = *(const bf16x8*)&xbf[arow*XBSTR + ks*32 + ak8];
        acc0 = __builtin_amdgcn_mfma_f32_16x16x32_bf16(a0, Bd[k4], acc0, 0, 0, 0);
        bf16x8 a1 = *(const bf16x8*)&xbf[rowT*XBSTR + ks*32 + ak8];
        acc1 = __builtin_amdgcn_mfma_f32_16x16x32_bf16(a1, Bd[k4], acc1, 0, 0, 0);
      }
    }
    const float s0 = fsilu(acc0[0]*a1r + b1r);
    const float s1 = fsilu(acc0[1]*a1r + b1r);
    const float s2 = fsilu(acc0[2]*a1r + b1r);
    const float s3 = fsilu(acc0[3]*a1r + b1r);
    uint2 u; u.x = f2bf2(s0, s1); u.y = f2bf2(s2, s3);
    *(uint2*)&xdT[colA*XDT + (l>>4)*4] = u;          // rows (l>>4)*4..+3 of column colA
    if ((l >> 4) == 0)
      xdT[colA*XDT + 16] = f2bf(fsilu(acc1[0]*a1r + b1r));
  }
  __syncthreads();                                   // bar2: A -> B1 (xdT cross-wave)

  // ---- prefetch B2 weight frags (latency covered by B1 + bar3) ----
  bf16x8 BcT[2][2];
  #pragma unroll
  for (int t = 0; t < 2; ++t)
    #pragma unroll
    for (int ks = 0; ks < 2; ++ks)
      BcT[t][ks] = get_bc<USE_WS>(wsf, Wc, wv*2 + t, ks, l);

  // ---- Phase B1 (split): wave wv computes group g=wv; wave 0 also g=4 ----
  {
    const int i = l;
    #define XDV(r) bf2f(xdT[i*XDT + (r)])
    if (wv == 0) {
      mbf[0*MSTR + i] = f2bf((XDV(0)+XDV(1)+XDV(2)+XDV(3)+XDV(4))*0.2f);
      mbf[4*MSTR + i] = f2bf((XDV(12)+XDV(14)+XDV(16))*(1.f/3.f));
    } else if (wv == 1) {
      mbf[1*MSTR + i] = f2bf((XDV(5)+XDV(7)+XDV(9))*(1.f/3.f));
    } else if (wv == 2) {
      mbf[2*MSTR + i] = f2bf((XDV(6)+XDV(8)+XDV(10))*(1.f/3.f));
    } else {
      mbf[3*MSTR + i] = f2bf((XDV(11)+XDV(13)+XDV(15))*(1.f/3.f));
    }
    #undef XDV
  }
  __syncthreads();                                   // bar3: B1 -> B2 (mbf cross-wave)

  // ---- Phase B2 (MFMA): mw = means @ [Wc1|Wc2], M=5, N=128, wave owns 2 n-tiles ----
  {
    bf16x8 am[2];
    #pragma unroll
    for (int ks = 0; ks < 2; ++ks)
      am[ks] = *(const bf16x8*)&mbf[arow*MSTR + ks*32 + ak8];
    #pragma unroll
    for (int t = 0; t < 2; ++t) {
      const int nt = wv*2 + t;
      f32x4 acc = {0.f,0.f,0.f,0.f};
      #pragma unroll
      for (int ks = 0; ks < 2; ++ks)
        acc = __builtin_amdgcn_mfma_f32_16x16x32_bf16(am[ks], BcT[t][ks], acc, 0, 0, 0);
      if ((l >> 4) == 0) {
        #pragma unroll
        for (int j = 0; j < 4; ++j) mw[j*MWC + nt*16 + arow] = acc[j];
      } else if ((l >> 4) == 1) {
        mw[4*MWC + nt*16 + arow] = acc[0];
      }
    }
  }
  __syncthreads();                                   // bar4: B2 -> B3 (mw cross-wave)

  // ---- prefetch all phase-E weight frags (latency covered by B3 + bar5) ----
  bf16x8 BaT[4][2];
  #pragma unroll
  for (int t = 0; t < 4; ++t)
    #pragma unroll
    for (int ks = 0; ks < 2; ++ks)
      BaT[t][ks] = get_ba<USE_WS>(wsf, Wa, wv*4 + t, ks, l);

  // ---- Phase B3 (split): wave wv computes g=wv; wave 0 also g=4 ----
  {
    const int o = l;
    float m2c[5];
    #pragma unroll
    for (int cc = 0; cc < 5; ++cc) m2c[cc] = mw[cc*MWC + 64 + o];
    auto doG = [&](int g){
      const float bse = mw[g*MWC + o] - m2c[g];
      float s = 0.f;
      #pragma unroll
      for (int cc = 0; cc < 5; ++cc) {
        if (cc != g) s += fsilu((bse + m2c[cc])*a2r + b2r);
      }
      abf[g*MSTR + o] = f2bf(s);
    };
    if (wv == 0) { doG(0); doG(4); }
    else if (wv == 1) doG(1);
    else if (wv == 2) doG(2);
    else doG(3);
  }
  __syncthreads();                                   // bar5: B3 -> E (abf cross-wave)

  // ---- Phase E (MFMA): att = sigmoid(agg @ Wa + ba), M=5, N=256, wave owns 4 n-tiles ----
  // epilogue: sigmoid only where g<5 (quartet 0: g=0..3; quartet 1: g=4)
  {
    bf16x8 ae[2];
    #pragma unroll
    for (int ks = 0; ks < 2; ++ks)
      ae[ks] = *(const bf16x8*)&abf[arow*MSTR + ks*32 + ak8];
    #pragma unroll
    for (int t = 0; t < 4; ++t) {
      const int nt = wv*4 + t;
      const int colE = nt*16 + arow;
      f32x4 acc = {0.f,0.f,0.f,0.f};
      #pragma unroll
      for (int ks = 0; ks < 2; ++ks)
        acc = __builtin_amdgcn_mfma_f32_16x16x32_bf16(ae[ks], BaT[t][ks], acc, 0, 0, 0);
      const float bav = ba[colE];
      const int q4 = l >> 4;
      if (q4 == 0) {
        #pragma unroll
        for (int j = 0; j < 4; ++j)
          att[j*ATS + colE] = f2bf(fsigm(acc[j] + bav));
      } else if (q4 == 1) {
        att[4*ATS + colE] = f2bf(fsigm(acc[0] + bav));
      }
    }
  }
  __syncthreads();                                   // bar6: E -> F

  // ---- Phase F: out[r][c4..c4+3] = x_f32(regs) * att[GOF[r]][c4..c4+3], dwordx4 stores ----
  {
    float* og = out + (size_t)b*4352;
    constexpr int GOF[17] = {0,0,0,0,0,1,2,1,2,1,2,3,4,3,4,3,4};
    auto emit = [&](v4f xv, int k){
      const bf16x4 a4 = *(const bf16x4*)&att[GOF[k]*ATS + c4];
      v4f o;
      o.x = xv.x * bf2f(a4[0]);
      o.y = xv.y * bf2f(a4[1]);
      o.z = xv.z * bf2f(a4[2]);
      o.w = xv.w * bf2f(a4[3]);
      *(v4f*)&og[k*256 + c4] = o;
    };
    emit(xr0, r0);      emit(xr1, r0 + 4);
    emit(xr2, r0 + 8);  emit(xr3, r0 + 12);
    if (tid < 64) emit(xr4, 16);
  }
}

extern "C" void kernel_launch(void* const* d_in, const int* in_sizes, int n_in,
                              void* d_out, int out_size, void* d_ws, size_t ws_size,
                              hipStream_t stream) {
    (void)n_in; (void)out_size;
    const float* x   = (const float*)d_in[0];
    const float* Wd  = (const float*)d_in[1];
    const float* bd  = (const float*)d_in[2];
    const float* s1  = (const float*)d_in[3];
    const float* b1  = (const float*)d_in[4];
    const float* m1  = (const float*)d_in[5];
    const float* v1  = (const float*)d_in[6];
    const float* Wc  = (const float*)d_in[7];
    const float* s2  = (const float*)d_in[8];
    const float* b2  = (const float*)d_in[9];
    const float* m2  = (const float*)d_in[10];
    const float* v2  = (const float*)d_in[11];
    const float* Wa  = (const float*)d_in[12];
    const float* ba  = (const float*)d_in[13];

    const int Btot = in_sizes[0] / (17 * 256);   // 4096 -> one block per batch
    bf16x8* wsf = (bf16x8*)d_ws;

    if (ws_size >= (size_t)FRAG_SLOTS * 16) {
        pack_frags<<<FRAG_SLOTS/256, 256, 0, stream>>>(Wd, Wc, Wa, wsf);
        fused_gnn_v12<true><<<Btot, 256, 0, stream>>>(
            x, Wd, bd, s1, b1, m1, v1, Wc, s2, b2, m2, v2, Wa, ba,
            wsf, (float*)d_out);
    } else {
        fused_gnn_v12<false><<<Btot, 256, 0, stream>>>(
            x, Wd, bd, s1, b1, m1, v1, Wc, s2, b2, m2, v2, Wa, ba,
            wsf, (float*)d_out);
    }
}